// Round 15
// baseline (125.906 us; speedup 1.0000x reference)
//
#include <hip/hip_runtime.h>
#include <math.h>

#define DIM 64
#define SEQ 784
#define BATCH 256
// 7 groups x 112 rows; group split into 14 blocks of 8 steps.
// step m (0..111) -> t = T0 - m (T0 = 783-112g), LDS row r = 111 - m.
// group g covers t in [672-112g, 783-112g]; base(g) = 672-112g.
// 16 waves: wave 0 scanner; waves 1..14 producers (8 rows each, own-block
// gram); wave 15 barrier-only.

// ---------- cross-lane helpers (wave64 reduction via DPP) ----------
template <int CTRL>
__device__ __forceinline__ float dpp_add_step(float s) {
    int v = __builtin_amdgcn_update_dpp(0, __float_as_int(s), CTRL, 0xF, 0xF, false);
    return s + __int_as_float(v);
}

// Sum across all 64 lanes; result broadcast (uniform, via readlane 63).
__device__ __forceinline__ float wave_allsum(float x) {
    x = dpp_add_step<0xB1>(x);   // xor 1
    x = dpp_add_step<0x4E>(x);   // xor 2
    x = dpp_add_step<0x141>(x);  // row_half_mirror
    x = dpp_add_step<0x140>(x);  // row_mirror
    x = dpp_add_step<0x142>(x);  // row_bcast15
    x = dpp_add_step<0x143>(x);  // row_bcast31
    return __int_as_float(__builtin_amdgcn_readlane(__float_as_int(x), 63));
}

// 16-lane row allsum (replicated layout): 4 DPP steps, uniform result, no readlane.
__device__ __forceinline__ float row16_allsum(float x) {
    x = dpp_add_step<0xB1>(x);
    x = dpp_add_step<0x4E>(x);
    x = dpp_add_step<0x141>(x);
    x = dpp_add_step<0x140>(x);
    return x;
}

__device__ __forceinline__ float dot4(float4 a, float4 b) {
    return fmaf(a.w, b.w, fmaf(a.z, b.z, fmaf(a.y, b.y, a.x * b.x)));
}

__device__ __forceinline__ float gelu_exact(float v) {
    return 0.5f * v * (1.0f + erff(v * 0.70710678118654752440f));
}

// Zero-instruction wave-local LDS ordering (compile-time only; same-wave DS
// ops complete in order in HW). Validated R5-R12.
#define WAVE_FENCE()                                                \
    do {                                                            \
        __builtin_amdgcn_wave_barrier();                            \
        asm volatile("" ::: "memory");                              \
    } while (0)

// ---------- fused kernel: one block (16 waves) per batch ----------
__global__ __launch_bounds__(1024, 1) void fused_all(
    const float* __restrict__ x, const float* __restrict__ W_in,
    const float* __restrict__ pos_emb, const float* __restrict__ Wq,
    const float* __restrict__ Wk, const float* __restrict__ Wv,
    const float* __restrict__ Wb, const float* __restrict__ bbp,
    const float* __restrict__ ln_g, const float* __restrict__ ln_b,
    const float* __restrict__ Wc, const float* __restrict__ bc,
    float* __restrict__ out)
{
    const int lane = threadIdx.x & 63;
    const int wv   = threadIdx.x >> 6;     // 0..15
    const int b    = blockIdx.x;

    __shared__ __align__(16) float kbuf[2][112][64];     // 57,344 B (double buffer)
    __shared__ __align__(16) float G_blk[2][14][8][8];   // 7,168 B Gram (i<j valid)
    __shared__ __align__(16) float al_lds[SEQ];          // alpha (absolute t)
    __shared__ __align__(16) float a_lds[SEQ];           // a output (absolute t)
    __shared__ __align__(16) float hb16[2][14][8][64];   // 57,344 B h rows (dbuf)
    __shared__ __align__(16) float sh[64];               // wave-0 scratch
    __shared__ __align__(16) float swr[16][64];          // wsum block reduce

    const float win = W_in[lane];

    // ---- producer constants (waves 1-14; harmless for others) ----
    float4 wkr[16];
    {
        const float4* wk4 = (const float4*)(Wk + lane * 64);
#pragma unroll
        for (int i = 0; i < 16; ++i) wkr[i] = wk4[i];
    }
    const float bb = bbp[0];
    const float4 wb4 = ((const float4*)Wb)[lane & 15];   // replicated slice

    // produce 8 rows of group g into kbuf[buf]; h rows into hb16[g&1]
    // (R12's validated double-buffer scheme). Phase C = R12 LDS-broadcast
    // GEMV (R14's readlane variant was slower: VALU-issue cost > LDS cost).
    auto produce = [&](int g, int buf) {
        const int base = 672 - 112 * g;
        const int r0   = (wv - 1) * 8;
        float (*hw)[64] = hb16[g & 1][wv - 1];
        // ---- A ----
#pragma unroll
        for (int i = 0; i < 8; ++i) {
            const int s = base + r0 + i;
            const float h = gelu_exact(fmaf(x[b * SEQ + s], win, pos_emb[s * 64 + lane]));
            hw[i][lane] = h;
        }
        WAVE_FENCE();
        // ---- B ---- (lane-group gr handles row ib*4+gr; replicated reads)
        float bd[2];
#pragma unroll
        for (int ib = 0; ib < 2; ++ib) {
            const int i = ib * 4 + (lane >> 4);
            const float4 h4 = ((const float4*)hw[i])[lane & 15];
            bd[ib] = row16_allsum(dot4(h4, wb4));
        }
        // ---- C ---- broadcast-read GEMV (R12 verbatim math)
#pragma unroll
        for (int i = 0; i < 8; ++i) {
            const float4* h4 = (const float4*)hw[i];
            float acc = 0.f;
#pragma unroll
            for (int j = 0; j < 16; ++j) {
                const float4 hv = h4[j], wk = wkr[j];
                acc = fmaf(hv.x, wk.x, acc);
                acc = fmaf(hv.y, wk.y, acc);
                acc = fmaf(hv.z, wk.z, acc);
                acc = fmaf(hv.w, wk.w, acc);
            }
            kbuf[buf][r0 + i][lane] = acc;
        }
        WAVE_FENCE();
        // ---- D + E ----
#pragma unroll
        for (int ib = 0; ib < 2; ++ib) {
            const int i = ib * 4 + (lane >> 4);
            const float4 k4 = ((const float4*)kbuf[buf][r0 + i])[lane & 15];
            float lam = row16_allsum(dot4(k4, k4));
            lam = fmaxf(lam, 1e-6f);
            const float beta = 1.0f / (1.0f + expf(-(bd[ib] + bb)));
            const float al   = -expm1f(-beta * lam) / (lam + 1e-6f);
            if ((lane & 15) == 0) al_lds[base + r0 + i] = al;
        }
    };

    // gram for THIS wave's own block (beta = 14-wv): its 8 produced rows
    // are exactly LDS rows [104-8*beta, 111-8*beta]. Wave-local.
    auto gram1 = [&](int buf) {
        const int beta = 14 - wv;          // wv 1..14 -> beta 13..0
        const int rb   = 111 - 8 * beta;
#pragma unroll
        for (int i = 0; i < 7; ++i) {
            const float4 kI = ((const float4*)kbuf[buf][rb - i])[lane & 15];
#pragma unroll
            for (int jb = i + 1; jb <= 7; jb += 4) {
                const int j  = jb + (lane >> 4);
                const int jc = (j <= 7) ? j : 7;
                const float4 kJ = ((const float4*)kbuf[buf][rb - jc])[lane & 15];
                const float gv = row16_allsum(dot4(kI, kJ));
                if ((lane & 15) == 0 && j <= 7)
                    G_blk[buf][beta][i][j] = gv;
            }
        }
    };

    // wsum for this wave's 8 rows of group g, from STORED h in hb16[g&1].
    // R12's validated ordering: read of parity g&1 at iteration g+1 precedes
    // produce(g+2)'s overwrite of that parity in program order.
    float w = 0.f;
    auto wsum8 = [&](int g) {
        const int base = 672 - 112 * g;
        const int r0   = (wv - 1) * 8;
        const float (*hw)[64] = hb16[g & 1][wv - 1];
#pragma unroll
        for (int i = 0; i < 8; ++i)
            w = fmaf(a_lds[base + r0 + i], hw[i][lane], w);
    };

    // ---- phase 0: wave0 u-init || producers produce(0)+gram1(0) ----
    float4 uq = make_float4(0.f, 0.f, 0.f, 0.f);
    if (wv == 0) {
        const float h = gelu_exact(fmaf(x[b * SEQ + 783], win, pos_emb[783 * 64 + lane]));
        sh[lane] = h;
        WAVE_FENCE();
        float u = 0.f;
        const float4* wq4 = (const float4*)(Wq + lane * 64);
        const float4* h4  = (const float4*)sh;
#pragma unroll
        for (int i = 0; i < 16; ++i) {
            float4 hv = h4[i], qv = wq4[i];
            u = fmaf(hv.x, qv.x, u);
            u = fmaf(hv.y, qv.y, u);
            u = fmaf(hv.z, qv.z, u);
            u = fmaf(hv.w, qv.w, u);
        }
        WAVE_FENCE();
        sh[lane] = u;
        WAVE_FENCE();
        uq = ((const float4*)sh)[lane & 15];   // replicated slice layout
    } else if (wv <= 14) {
        produce(0, 0);
        WAVE_FENCE();
        gram1(0);
    }
    __syncthreads();

    // oct-Gram scan block (R10 verbatim, validated)
    auto scan8 = [&](int buf, int T0, int beta) {
        const int rb = 111 - 8 * beta;
        const int T  = T0 - 8 * beta;
        const float4 k0 = ((const float4*)kbuf[buf][rb    ])[lane & 15];
        const float4 k1 = ((const float4*)kbuf[buf][rb - 1])[lane & 15];
        const float4 k2 = ((const float4*)kbuf[buf][rb - 2])[lane & 15];
        const float4 k3 = ((const float4*)kbuf[buf][rb - 3])[lane & 15];
        const float4 k4 = ((const float4*)kbuf[buf][rb - 4])[lane & 15];
        const float4 k5 = ((const float4*)kbuf[buf][rb - 5])[lane & 15];
        const float4 k6 = ((const float4*)kbuf[buf][rb - 6])[lane & 15];
        const float4 k7 = ((const float4*)kbuf[buf][rb - 7])[lane & 15];
        const float4 avH = *(const float4*)&al_lds[T - 3];  // al0=.w .. al3=.x
        const float4 avL = *(const float4*)&al_lds[T - 7];  // al4=.w .. al7=.x
        const float* Gb = &G_blk[buf][beta][0][0];
        const float g01 = Gb[1],  g02 = Gb[2],  g03 = Gb[3],  g04 = Gb[4];
        const float g05 = Gb[5],  g06 = Gb[6],  g07 = Gb[7];
        const float g12 = Gb[10], g13 = Gb[11], g14 = Gb[12], g15 = Gb[13];
        const float g16 = Gb[14], g17 = Gb[15];
        const float g23 = Gb[19], g24 = Gb[20], g25 = Gb[21], g26 = Gb[22];
        const float g27 = Gb[23];
        const float g34 = Gb[28], g35 = Gb[29], g36 = Gb[30], g37 = Gb[31];
        const float g45 = Gb[37], g46 = Gb[38], g47 = Gb[39];
        const float g56 = Gb[46], g57 = Gb[47];
        const float g67 = Gb[55];
        const float D0 = row16_allsum(dot4(uq, k0));
        const float D1 = row16_allsum(dot4(uq, k1));
        const float D2 = row16_allsum(dot4(uq, k2));
        const float D3 = row16_allsum(dot4(uq, k3));
        const float D4 = row16_allsum(dot4(uq, k4));
        const float D5 = row16_allsum(dot4(uq, k5));
        const float D6 = row16_allsum(dot4(uq, k6));
        const float D7 = row16_allsum(dot4(uq, k7));
        const float a0 = avH.w * D0;
        const float d1 = fmaf(-a0, g01, D1);
        const float a1 = avH.z * d1;
        const float d2 = fmaf(-a1, g12, fmaf(-a0, g02, D2));
        const float a2 = avH.y * d2;
        const float d3 = fmaf(-a2, g23, fmaf(-a1, g13, fmaf(-a0, g03, D3)));
        const float a3 = avH.x * d3;
        const float d4 = fmaf(-a3, g34, fmaf(-a2, g24, fmaf(-a1, g14, fmaf(-a0, g04, D4))));
        const float a4 = avL.w * d4;
        const float d5 = fmaf(-a4, g45, fmaf(-a3, g35, fmaf(-a2, g25, fmaf(-a1, g15, fmaf(-a0, g05, D5)))));
        const float a5 = avL.z * d5;
        const float d6 = fmaf(-a5, g56, fmaf(-a4, g46, fmaf(-a3, g36, fmaf(-a2, g26, fmaf(-a1, g16, fmaf(-a0, g06, D6))))));
        const float a6 = avL.y * d6;
        const float d7 = fmaf(-a6, g67, fmaf(-a5, g57, fmaf(-a4, g47, fmaf(-a3, g37, fmaf(-a2, g27, fmaf(-a1, g17, fmaf(-a0, g07, D7)))))));
        const float a7 = avL.x * d7;
        uq.x = fmaf(-a7, k7.x, fmaf(-a6, k6.x, fmaf(-a5, k5.x, fmaf(-a4, k4.x,
               fmaf(-a3, k3.x, fmaf(-a2, k2.x, fmaf(-a1, k1.x, fmaf(-a0, k0.x, uq.x))))))));
        uq.y = fmaf(-a7, k7.y, fmaf(-a6, k6.y, fmaf(-a5, k5.y, fmaf(-a4, k4.y,
               fmaf(-a3, k3.y, fmaf(-a2, k2.y, fmaf(-a1, k1.y, fmaf(-a0, k0.y, uq.y))))))));
        uq.z = fmaf(-a7, k7.z, fmaf(-a6, k6.z, fmaf(-a5, k5.z, fmaf(-a4, k4.z,
               fmaf(-a3, k3.z, fmaf(-a2, k2.z, fmaf(-a1, k1.z, fmaf(-a0, k0.z, uq.z))))))));
        uq.w = fmaf(-a7, k7.w, fmaf(-a6, k6.w, fmaf(-a5, k5.w, fmaf(-a4, k4.w,
               fmaf(-a3, k3.w, fmaf(-a2, k2.w, fmaf(-a1, k1.w, fmaf(-a0, k0.w, uq.w))))))));
        if (lane == 0) {
            *(float4*)&a_lds[T - 3] = make_float4(a3, a2, a1, a0);
            *(float4*)&a_lds[T - 7] = make_float4(a7, a6, a5, a4);
        }
    };

    // ---- main loop: wave0 scans g; producers wsum(g-1) + produce/gram(g+1) ----
#pragma unroll 1
    for (int g = 0; g < 7; ++g) {
        const int buf = g & 1;
        const int T0  = 783 - 112 * g;
        if (wv == 0) {
#pragma unroll 1
            for (int beta = 0; beta < 14; ++beta)
                scan8(buf, T0, beta);
        } else if (wv <= 14) {
            if (g >= 1) wsum8(g - 1);
            if (g < 6) {
                produce(g + 1, buf ^ 1);
                WAVE_FENCE();
                gram1(buf ^ 1);
            }
        }
        __syncthreads();
    }

    // ---- tail: producers wsum group 6 (a(6) barrier-ordered; h(6) in hb16[0]) ----
    if (wv >= 1 && wv <= 14) wsum8(6);
    swr[wv][lane] = (wv >= 1 && wv <= 14) ? w : 0.f;
    __syncthreads();
    if (wv != 0) return;

    // ---- wave-0 epilogue: last = Wv*w -> LN -> logits ----
    w = 0.f;
#pragma unroll
    for (int i = 0; i < 16; ++i) w += swr[i][lane];
    sh[lane] = w;
    WAVE_FENCE();
    float last = 0.f;
    const float4* wv4 = (const float4*)(Wv + lane * 64);
    const float4* w4  = (const float4*)sh;
#pragma unroll
    for (int i = 0; i < 16; ++i) {
        float4 hv = w4[i], vv = wv4[i];
        last = fmaf(hv.x, vv.x, last);
        last = fmaf(hv.y, vv.y, last);
        last = fmaf(hv.z, vv.z, last);
        last = fmaf(hv.w, vv.w, last);
    }
    const float mu  = wave_allsum(last) * 0.015625f;
    const float dd  = last - mu;
    const float var = wave_allsum(dd * dd) * 0.015625f;
    const float ln  = dd / sqrtf(var + 1e-5f) * ln_g[lane] + ln_b[lane];
    WAVE_FENCE();
    sh[lane] = ln;
    WAVE_FENCE();
    if (lane < 10) {
        float acc = bc[lane];
        const float* wc = Wc + lane * 64;
#pragma unroll
        for (int j = 0; j < 64; ++j) acc = fmaf(wc[j], sh[j], acc);
        out[b * 10 + lane] = acc;
    }
}

extern "C" void kernel_launch(void* const* d_in, const int* in_sizes, int n_in,
                              void* d_out, int out_size, void* d_ws, size_t ws_size,
                              hipStream_t stream)
{
    const float* x       = (const float*)d_in[0];
    const float* W_in    = (const float*)d_in[1];
    const float* pos_emb = (const float*)d_in[2];
    const float* Wq      = (const float*)d_in[3];
    const float* Wk      = (const float*)d_in[4];
    const float* Wv      = (const float*)d_in[5];
    const float* Wb      = (const float*)d_in[6];
    const float* bb      = (const float*)d_in[7];
    const float* ln_g    = (const float*)d_in[8];
    const float* ln_b    = (const float*)d_in[9];
    const float* Wc      = (const float*)d_in[10];
    const float* bc      = (const float*)d_in[11];
    float* out = (float*)d_out;

    fused_all<<<BATCH, 1024, 0, stream>>>(x, W_in, pos_emb, Wq, Wk, Wv, Wb, bb,
                                          ln_g, ln_b, Wc, bc, out);
}

// Round 16
// 125.363 us; speedup vs baseline: 1.0043x; 1.0043x over previous
//
#include <hip/hip_runtime.h>
#include <math.h>

#define DIM 64
#define SEQ 784
#define BATCH 256
// 7 groups x 112 rows; group split into 14 blocks of 8 steps.
// step m (0..111) -> t = T0 - m (T0 = 783-112g), LDS row r = 111 - m.
// group g covers t in [672-112g, 783-112g]; base(g) = 672-112g.
// 16 waves: wave 0 scanner; waves 1..14 producers (8 rows each, own-block
// gram); wave 15 barrier-only.
// __launch_bounds__(1024, 4): 4 waves/EU declared -> 128-VGPR budget.
// R15's (1024,1) let the compiler pick 64 VGPRs -> wkr[16] spilled to
// scratch (FETCH_SIZE 125 MB of spill reads). This is the one-line fix.

// ---------- cross-lane helpers (wave64 reduction via DPP) ----------
template <int CTRL>
__device__ __forceinline__ float dpp_add_step(float s) {
    int v = __builtin_amdgcn_update_dpp(0, __float_as_int(s), CTRL, 0xF, 0xF, false);
    return s + __int_as_float(v);
}

// Sum across all 64 lanes; result broadcast (uniform, via readlane 63).
__device__ __forceinline__ float wave_allsum(float x) {
    x = dpp_add_step<0xB1>(x);   // xor 1
    x = dpp_add_step<0x4E>(x);   // xor 2
    x = dpp_add_step<0x141>(x);  // row_half_mirror
    x = dpp_add_step<0x140>(x);  // row_mirror
    x = dpp_add_step<0x142>(x);  // row_bcast15
    x = dpp_add_step<0x143>(x);  // row_bcast31
    return __int_as_float(__builtin_amdgcn_readlane(__float_as_int(x), 63));
}

// 16-lane row allsum (replicated layout): 4 DPP steps, uniform result, no readlane.
__device__ __forceinline__ float row16_allsum(float x) {
    x = dpp_add_step<0xB1>(x);
    x = dpp_add_step<0x4E>(x);
    x = dpp_add_step<0x141>(x);
    x = dpp_add_step<0x140>(x);
    return x;
}

__device__ __forceinline__ float dot4(float4 a, float4 b) {
    return fmaf(a.w, b.w, fmaf(a.z, b.z, fmaf(a.y, b.y, a.x * b.x)));
}

__device__ __forceinline__ float gelu_exact(float v) {
    return 0.5f * v * (1.0f + erff(v * 0.70710678118654752440f));
}

// Zero-instruction wave-local LDS ordering (compile-time only; same-wave DS
// ops complete in order in HW). Validated R5-R15.
#define WAVE_FENCE()                                                \
    do {                                                            \
        __builtin_amdgcn_wave_barrier();                            \
        asm volatile("" ::: "memory");                              \
    } while (0)

// ---------- fused kernel: one block (16 waves) per batch ----------
__global__ __launch_bounds__(1024, 4) void fused_all(
    const float* __restrict__ x, const float* __restrict__ W_in,
    const float* __restrict__ pos_emb, const float* __restrict__ Wq,
    const float* __restrict__ Wk, const float* __restrict__ Wv,
    const float* __restrict__ Wb, const float* __restrict__ bbp,
    const float* __restrict__ ln_g, const float* __restrict__ ln_b,
    const float* __restrict__ Wc, const float* __restrict__ bc,
    float* __restrict__ out)
{
    const int lane = threadIdx.x & 63;
    const int wv   = threadIdx.x >> 6;     // 0..15
    const int b    = blockIdx.x;

    __shared__ __align__(16) float kbuf[2][112][64];     // 57,344 B (double buffer)
    __shared__ __align__(16) float G_blk[2][14][8][8];   // 7,168 B Gram (i<j valid)
    __shared__ __align__(16) float al_lds[SEQ];          // alpha (absolute t)
    __shared__ __align__(16) float a_lds[SEQ];           // a output (absolute t)
    __shared__ __align__(16) float hb16[2][14][8][64];   // 57,344 B h rows (dbuf)
    __shared__ __align__(16) float sh[64];               // wave-0 scratch
    __shared__ __align__(16) float swr[16][64];          // wsum block reduce

    const float win = W_in[lane];

    // ---- producer constants (waves 1-14; harmless for others) ----
    float4 wkr[16];
    {
        const float4* wk4 = (const float4*)(Wk + lane * 64);
#pragma unroll
        for (int i = 0; i < 16; ++i) wkr[i] = wk4[i];
    }
    const float bb = bbp[0];
    const float4 wb4 = ((const float4*)Wb)[lane & 15];   // replicated slice

    // produce 8 rows of group g into kbuf[buf]; h rows into hb16[g&1]
    // (R12's validated double-buffer scheme). Phase C = R12 LDS-broadcast
    // GEMV (R14's readlane variant was slower: VALU-issue cost > LDS cost).
    auto produce = [&](int g, int buf) {
        const int base = 672 - 112 * g;
        const int r0   = (wv - 1) * 8;
        float (*hw)[64] = hb16[g & 1][wv - 1];
        // ---- A ----
#pragma unroll
        for (int i = 0; i < 8; ++i) {
            const int s = base + r0 + i;
            const float h = gelu_exact(fmaf(x[b * SEQ + s], win, pos_emb[s * 64 + lane]));
            hw[i][lane] = h;
        }
        WAVE_FENCE();
        // ---- B ---- (lane-group gr handles row ib*4+gr; replicated reads)
        float bd[2];
#pragma unroll
        for (int ib = 0; ib < 2; ++ib) {
            const int i = ib * 4 + (lane >> 4);
            const float4 h4 = ((const float4*)hw[i])[lane & 15];
            bd[ib] = row16_allsum(dot4(h4, wb4));
        }
        // ---- C ---- broadcast-read GEMV (R12 verbatim math)
#pragma unroll
        for (int i = 0; i < 8; ++i) {
            const float4* h4 = (const float4*)hw[i];
            float acc = 0.f;
#pragma unroll
            for (int j = 0; j < 16; ++j) {
                const float4 hv = h4[j], wk = wkr[j];
                acc = fmaf(hv.x, wk.x, acc);
                acc = fmaf(hv.y, wk.y, acc);
                acc = fmaf(hv.z, wk.z, acc);
                acc = fmaf(hv.w, wk.w, acc);
            }
            kbuf[buf][r0 + i][lane] = acc;
        }
        WAVE_FENCE();
        // ---- D + E ----
#pragma unroll
        for (int ib = 0; ib < 2; ++ib) {
            const int i = ib * 4 + (lane >> 4);
            const float4 k4 = ((const float4*)kbuf[buf][r0 + i])[lane & 15];
            float lam = row16_allsum(dot4(k4, k4));
            lam = fmaxf(lam, 1e-6f);
            const float beta = 1.0f / (1.0f + expf(-(bd[ib] + bb)));
            const float al   = -expm1f(-beta * lam) / (lam + 1e-6f);
            if ((lane & 15) == 0) al_lds[base + r0 + i] = al;
        }
    };

    // gram for THIS wave's own block (beta = 14-wv): its 8 produced rows
    // are exactly LDS rows [104-8*beta, 111-8*beta]. Wave-local.
    auto gram1 = [&](int buf) {
        const int beta = 14 - wv;          // wv 1..14 -> beta 13..0
        const int rb   = 111 - 8 * beta;
#pragma unroll
        for (int i = 0; i < 7; ++i) {
            const float4 kI = ((const float4*)kbuf[buf][rb - i])[lane & 15];
#pragma unroll
            for (int jb = i + 1; jb <= 7; jb += 4) {
                const int j  = jb + (lane >> 4);
                const int jc = (j <= 7) ? j : 7;
                const float4 kJ = ((const float4*)kbuf[buf][rb - jc])[lane & 15];
                const float gv = row16_allsum(dot4(kI, kJ));
                if ((lane & 15) == 0 && j <= 7)
                    G_blk[buf][beta][i][j] = gv;
            }
        }
    };

    // wsum for this wave's 8 rows of group g, from STORED h in hb16[g&1].
    // R12's validated ordering: read of parity g&1 at iteration g+1 precedes
    // produce(g+2)'s overwrite of that parity in program order.
    float w = 0.f;
    auto wsum8 = [&](int g) {
        const int base = 672 - 112 * g;
        const int r0   = (wv - 1) * 8;
        const float (*hw)[64] = hb16[g & 1][wv - 1];
#pragma unroll
        for (int i = 0; i < 8; ++i)
            w = fmaf(a_lds[base + r0 + i], hw[i][lane], w);
    };

    // ---- phase 0: wave0 u-init || producers produce(0)+gram1(0) ----
    float4 uq = make_float4(0.f, 0.f, 0.f, 0.f);
    if (wv == 0) {
        const float h = gelu_exact(fmaf(x[b * SEQ + 783], win, pos_emb[783 * 64 + lane]));
        sh[lane] = h;
        WAVE_FENCE();
        float u = 0.f;
        const float4* wq4 = (const float4*)(Wq + lane * 64);
        const float4* h4  = (const float4*)sh;
#pragma unroll
        for (int i = 0; i < 16; ++i) {
            float4 hv = h4[i], qv = wq4[i];
            u = fmaf(hv.x, qv.x, u);
            u = fmaf(hv.y, qv.y, u);
            u = fmaf(hv.z, qv.z, u);
            u = fmaf(hv.w, qv.w, u);
        }
        WAVE_FENCE();
        sh[lane] = u;
        WAVE_FENCE();
        uq = ((const float4*)sh)[lane & 15];   // replicated slice layout
    } else if (wv <= 14) {
        produce(0, 0);
        WAVE_FENCE();
        gram1(0);
    }
    __syncthreads();

    // oct-Gram scan block (R10 verbatim, validated)
    auto scan8 = [&](int buf, int T0, int beta) {
        const int rb = 111 - 8 * beta;
        const int T  = T0 - 8 * beta;
        const float4 k0 = ((const float4*)kbuf[buf][rb    ])[lane & 15];
        const float4 k1 = ((const float4*)kbuf[buf][rb - 1])[lane & 15];
        const float4 k2 = ((const float4*)kbuf[buf][rb - 2])[lane & 15];
        const float4 k3 = ((const float4*)kbuf[buf][rb - 3])[lane & 15];
        const float4 k4 = ((const float4*)kbuf[buf][rb - 4])[lane & 15];
        const float4 k5 = ((const float4*)kbuf[buf][rb - 5])[lane & 15];
        const float4 k6 = ((const float4*)kbuf[buf][rb - 6])[lane & 15];
        const float4 k7 = ((const float4*)kbuf[buf][rb - 7])[lane & 15];
        const float4 avH = *(const float4*)&al_lds[T - 3];  // al0=.w .. al3=.x
        const float4 avL = *(const float4*)&al_lds[T - 7];  // al4=.w .. al7=.x
        const float* Gb = &G_blk[buf][beta][0][0];
        const float g01 = Gb[1],  g02 = Gb[2],  g03 = Gb[3],  g04 = Gb[4];
        const float g05 = Gb[5],  g06 = Gb[6],  g07 = Gb[7];
        const float g12 = Gb[10], g13 = Gb[11], g14 = Gb[12], g15 = Gb[13];
        const float g16 = Gb[14], g17 = Gb[15];
        const float g23 = Gb[19], g24 = Gb[20], g25 = Gb[21], g26 = Gb[22];
        const float g27 = Gb[23];
        const float g34 = Gb[28], g35 = Gb[29], g36 = Gb[30], g37 = Gb[31];
        const float g45 = Gb[37], g46 = Gb[38], g47 = Gb[39];
        const float g56 = Gb[46], g57 = Gb[47];
        const float g67 = Gb[55];
        const float D0 = row16_allsum(dot4(uq, k0));
        const float D1 = row16_allsum(dot4(uq, k1));
        const float D2 = row16_allsum(dot4(uq, k2));
        const float D3 = row16_allsum(dot4(uq, k3));
        const float D4 = row16_allsum(dot4(uq, k4));
        const float D5 = row16_allsum(dot4(uq, k5));
        const float D6 = row16_allsum(dot4(uq, k6));
        const float D7 = row16_allsum(dot4(uq, k7));
        const float a0 = avH.w * D0;
        const float d1 = fmaf(-a0, g01, D1);
        const float a1 = avH.z * d1;
        const float d2 = fmaf(-a1, g12, fmaf(-a0, g02, D2));
        const float a2 = avH.y * d2;
        const float d3 = fmaf(-a2, g23, fmaf(-a1, g13, fmaf(-a0, g03, D3)));
        const float a3 = avH.x * d3;
        const float d4 = fmaf(-a3, g34, fmaf(-a2, g24, fmaf(-a1, g14, fmaf(-a0, g04, D4))));
        const float a4 = avL.w * d4;
        const float d5 = fmaf(-a4, g45, fmaf(-a3, g35, fmaf(-a2, g25, fmaf(-a1, g15, fmaf(-a0, g05, D5)))));
        const float a5 = avL.z * d5;
        const float d6 = fmaf(-a5, g56, fmaf(-a4, g46, fmaf(-a3, g36, fmaf(-a2, g26, fmaf(-a1, g16, fmaf(-a0, g06, D6))))));
        const float a6 = avL.y * d6;
        const float d7 = fmaf(-a6, g67, fmaf(-a5, g57, fmaf(-a4, g47, fmaf(-a3, g37, fmaf(-a2, g27, fmaf(-a1, g17, fmaf(-a0, g07, D7)))))));
        const float a7 = avL.x * d7;
        uq.x = fmaf(-a7, k7.x, fmaf(-a6, k6.x, fmaf(-a5, k5.x, fmaf(-a4, k4.x,
               fmaf(-a3, k3.x, fmaf(-a2, k2.x, fmaf(-a1, k1.x, fmaf(-a0, k0.x, uq.x))))))));
        uq.y = fmaf(-a7, k7.y, fmaf(-a6, k6.y, fmaf(-a5, k5.y, fmaf(-a4, k4.y,
               fmaf(-a3, k3.y, fmaf(-a2, k2.y, fmaf(-a1, k1.y, fmaf(-a0, k0.y, uq.y))))))));
        uq.z = fmaf(-a7, k7.z, fmaf(-a6, k6.z, fmaf(-a5, k5.z, fmaf(-a4, k4.z,
               fmaf(-a3, k3.z, fmaf(-a2, k2.z, fmaf(-a1, k1.z, fmaf(-a0, k0.z, uq.z))))))));
        uq.w = fmaf(-a7, k7.w, fmaf(-a6, k6.w, fmaf(-a5, k5.w, fmaf(-a4, k4.w,
               fmaf(-a3, k3.w, fmaf(-a2, k2.w, fmaf(-a1, k1.w, fmaf(-a0, k0.w, uq.w))))))));
        if (lane == 0) {
            *(float4*)&a_lds[T - 3] = make_float4(a3, a2, a1, a0);
            *(float4*)&a_lds[T - 7] = make_float4(a7, a6, a5, a4);
        }
    };

    // ---- main loop: wave0 scans g; producers wsum(g-1) + produce/gram(g+1) ----
#pragma unroll 1
    for (int g = 0; g < 7; ++g) {
        const int buf = g & 1;
        const int T0  = 783 - 112 * g;
        if (wv == 0) {
#pragma unroll 1
            for (int beta = 0; beta < 14; ++beta)
                scan8(buf, T0, beta);
        } else if (wv <= 14) {
            if (g >= 1) wsum8(g - 1);
            if (g < 6) {
                produce(g + 1, buf ^ 1);
                WAVE_FENCE();
                gram1(buf ^ 1);
            }
        }
        __syncthreads();
    }

    // ---- tail: producers wsum group 6 (a(6) barrier-ordered; h(6) in hb16[0]) ----
    if (wv >= 1 && wv <= 14) wsum8(6);
    swr[wv][lane] = (wv >= 1 && wv <= 14) ? w : 0.f;
    __syncthreads();
    if (wv != 0) return;

    // ---- wave-0 epilogue: last = Wv*w -> LN -> logits ----
    w = 0.f;
#pragma unroll
    for (int i = 0; i < 16; ++i) w += swr[i][lane];
    sh[lane] = w;
    WAVE_FENCE();
    float last = 0.f;
    const float4* wv4 = (const float4*)(Wv + lane * 64);
    const float4* w4  = (const float4*)sh;
#pragma unroll
    for (int i = 0; i < 16; ++i) {
        float4 hv = w4[i], vv = wv4[i];
        last = fmaf(hv.x, vv.x, last);
        last = fmaf(hv.y, vv.y, last);
        last = fmaf(hv.z, vv.z, last);
        last = fmaf(hv.w, vv.w, last);
    }
    const float mu  = wave_allsum(last) * 0.015625f;
    const float dd  = last - mu;
    const float var = wave_allsum(dd * dd) * 0.015625f;
    const float ln  = dd / sqrtf(var + 1e-5f) * ln_g[lane] + ln_b[lane];
    WAVE_FENCE();
    sh[lane] = ln;
    WAVE_FENCE();
    if (lane < 10) {
        float acc = bc[lane];
        const float* wc = Wc + lane * 64;
#pragma unroll
        for (int j = 0; j < 64; ++j) acc = fmaf(wc[j], sh[j], acc);
        out[b * 10 + lane] = acc;
    }
}

extern "C" void kernel_launch(void* const* d_in, const int* in_sizes, int n_in,
                              void* d_out, int out_size, void* d_ws, size_t ws_size,
                              hipStream_t stream)
{
    const float* x       = (const float*)d_in[0];
    const float* W_in    = (const float*)d_in[1];
    const float* pos_emb = (const float*)d_in[2];
    const float* Wq      = (const float*)d_in[3];
    const float* Wk      = (const float*)d_in[4];
    const float* Wv      = (const float*)d_in[5];
    const float* Wb      = (const float*)d_in[6];
    const float* bb      = (const float*)d_in[7];
    const float* ln_g    = (const float*)d_in[8];
    const float* ln_b    = (const float*)d_in[9];
    const float* Wc      = (const float*)d_in[10];
    const float* bc      = (const float*)d_in[11];
    float* out = (float*)d_out;

    fused_all<<<BATCH, 1024, 0, stream>>>(x, W_in, pos_emb, Wq, Wk, Wv, Wb, bb,
                                          ln_g, ln_b, Wc, bc, out);
}

// Round 17
// 89.913 us; speedup vs baseline: 1.4003x; 1.3943x over previous
//
#include <hip/hip_runtime.h>
#include <math.h>

#define DIM 64
#define SEQ 784
#define BATCH 256
// 7 groups x 112 rows; group split into 14 blocks of 8 steps.
// step m (0..111) -> t = T0 - m (T0 = 783-112g), LDS row r = 111 - m.
// group g covers t in [672-112g, 783-112g]; base(g) = 672-112g.
// R17 = R12 verbatim (validated 89.85 us, absmax 9.5e-7): 512 thr, 8 waves,
// 120 VGPR, no spill. R13-R16 post-mortems: readlane-GEMV (+18 us, VALU
// issue > LDS broadcast cost), single-buffer hb16 (wrong, stale h), and
// 16-wave occupancy x2 (compiler pinned VGPR=64 and spilled wkr -> 125 MB
// scratch traffic; launch_bounds 2nd arg only caps, doesn't raise).

// ---------- cross-lane helpers (wave64 reduction via DPP) ----------
template <int CTRL>
__device__ __forceinline__ float dpp_add_step(float s) {
    int v = __builtin_amdgcn_update_dpp(0, __float_as_int(s), CTRL, 0xF, 0xF, false);
    return s + __int_as_float(v);
}

// Sum across all 64 lanes; result broadcast (uniform, via readlane 63).
__device__ __forceinline__ float wave_allsum(float x) {
    x = dpp_add_step<0xB1>(x);   // xor 1
    x = dpp_add_step<0x4E>(x);   // xor 2
    x = dpp_add_step<0x141>(x);  // row_half_mirror
    x = dpp_add_step<0x140>(x);  // row_mirror
    x = dpp_add_step<0x142>(x);  // row_bcast15
    x = dpp_add_step<0x143>(x);  // row_bcast31
    return __int_as_float(__builtin_amdgcn_readlane(__float_as_int(x), 63));
}

// 16-lane row allsum (replicated layout): 4 DPP steps, uniform result, no readlane.
__device__ __forceinline__ float row16_allsum(float x) {
    x = dpp_add_step<0xB1>(x);
    x = dpp_add_step<0x4E>(x);
    x = dpp_add_step<0x141>(x);
    x = dpp_add_step<0x140>(x);
    return x;
}

__device__ __forceinline__ float dot4(float4 a, float4 b) {
    return fmaf(a.w, b.w, fmaf(a.z, b.z, fmaf(a.y, b.y, a.x * b.x)));
}

__device__ __forceinline__ float gelu_exact(float v) {
    return 0.5f * v * (1.0f + erff(v * 0.70710678118654752440f));
}

// Zero-instruction wave-local LDS ordering (compile-time only; same-wave DS
// ops complete in order in HW). Validated R5-R12.
#define WAVE_FENCE()                                                \
    do {                                                            \
        __builtin_amdgcn_wave_barrier();                            \
        asm volatile("" ::: "memory");                              \
    } while (0)

// ---------- fused kernel: one block (8 waves) per batch ----------
// wave 0: scanner (oct-Gram blocks; Gram precomputed by producers)
// waves 1-7: wsum(g-1) from stored h (double-buffered), then produce(g+1)
// [batched phases A-E], then gram8 on their own rows (wave-local).
__global__ __launch_bounds__(512, 1) void fused_all(
    const float* __restrict__ x, const float* __restrict__ W_in,
    const float* __restrict__ pos_emb, const float* __restrict__ Wq,
    const float* __restrict__ Wk, const float* __restrict__ Wv,
    const float* __restrict__ Wb, const float* __restrict__ bbp,
    const float* __restrict__ ln_g, const float* __restrict__ ln_b,
    const float* __restrict__ Wc, const float* __restrict__ bc,
    float* __restrict__ out)
{
    const int lane = threadIdx.x & 63;
    const int wv   = threadIdx.x >> 6;     // 0..7
    const int b    = blockIdx.x;

    __shared__ __align__(16) float kbuf[2][112][64];     // 57,344 B (double buffer)
    __shared__ __align__(16) float G_blk[2][14][8][8];   // 7,168 B Gram (i<j valid)
    __shared__ __align__(16) float al_lds[SEQ];          // alpha (absolute t)
    __shared__ __align__(16) float a_lds[SEQ];           // a output (absolute t)
    __shared__ __align__(16) float hb16[2][7][16][64];   // 57,344 B h rows (dbuf)
    __shared__ __align__(16) float sh[64];               // wave-0 scratch
    __shared__ __align__(16) float swr[8][64];           // wsum block reduce

    const float win = W_in[lane];

    // ---- producer constants (waves 1-7; harmless for wave 0) ----
    float4 wkr[16];
    {
        const float4* wk4 = (const float4*)(Wk + lane * 64);
#pragma unroll
        for (int i = 0; i < 16; ++i) wkr[i] = wk4[i];
    }
    const float bb = bbp[0];
    const float4 wb4 = ((const float4*)Wb)[lane & 15];   // replicated slice

    // produce 16 rows of group g into kbuf[buf]; h rows into hb16[g&1]
    // (validated double-buffer). Batched phases A-E.
    auto produce = [&](int g, int buf) {
        const int base = 672 - 112 * g;
        const int r0   = (wv - 1) * 16;
        float (*hw)[64] = hb16[g & 1][wv - 1];
        // ---- A ----
#pragma unroll
        for (int i = 0; i < 16; ++i) {
            const int s = base + r0 + i;
            const float h = gelu_exact(fmaf(x[b * SEQ + s], win, pos_emb[s * 64 + lane]));
            hw[i][lane] = h;
        }
        WAVE_FENCE();
        // ---- B ---- (lane-group gr handles row ib*4+gr; replicated reads)
        float bd[4];
#pragma unroll
        for (int ib = 0; ib < 4; ++ib) {
            const int i = ib * 4 + (lane >> 4);
            const float4 h4 = ((const float4*)hw[i])[lane & 15];
            bd[ib] = row16_allsum(dot4(h4, wb4));
        }
        // ---- C ---- broadcast-read GEMV
#pragma unroll
        for (int i = 0; i < 16; ++i) {
            const float4* h4 = (const float4*)hw[i];
            float acc = 0.f;
#pragma unroll
            for (int j = 0; j < 16; ++j) {
                const float4 hv = h4[j], wk = wkr[j];
                acc = fmaf(hv.x, wk.x, acc);
                acc = fmaf(hv.y, wk.y, acc);
                acc = fmaf(hv.z, wk.z, acc);
                acc = fmaf(hv.w, wk.w, acc);
            }
            kbuf[buf][r0 + i][lane] = acc;
        }
        WAVE_FENCE();
        // ---- D + E ----
#pragma unroll
        for (int ib = 0; ib < 4; ++ib) {
            const int i = ib * 4 + (lane >> 4);
            const float4 k4 = ((const float4*)kbuf[buf][r0 + i])[lane & 15];
            float lam = row16_allsum(dot4(k4, k4));
            lam = fmaxf(lam, 1e-6f);
            const float beta = 1.0f / (1.0f + expf(-(bd[ib] + bb)));
            const float al   = -expm1f(-beta * lam) / (lam + 1e-6f);
            if ((lane & 15) == 0) al_lds[base + r0 + i] = al;
        }
    };

    // gram8: wave wv's produced rows are exactly blocks beta = 2*(7-wv)+{0,1}.
    auto gram8 = [&](int buf) {
#pragma unroll
        for (int blk = 0; blk < 2; ++blk) {
            const int beta = 2 * (7 - wv) + blk;
            const int rb   = 111 - 8 * beta;   // LDS row of block step 0
#pragma unroll
            for (int i = 0; i < 7; ++i) {
                const float4 kI = ((const float4*)kbuf[buf][rb - i])[lane & 15];
#pragma unroll
                for (int jb = i + 1; jb <= 7; jb += 4) {
                    const int j  = jb + (lane >> 4);
                    const int jc = (j <= 7) ? j : 7;
                    const float4 kJ = ((const float4*)kbuf[buf][rb - jc])[lane & 15];
                    const float gv = row16_allsum(dot4(kI, kJ));
                    if ((lane & 15) == 0 && j <= 7)
                        G_blk[buf][beta][i][j] = gv;
                }
            }
        }
    };

    // wsum for this wave's 16 rows of group g, from STORED h in hb16[g&1].
    // Validated ordering: at iteration g+1, this read of parity g&1 precedes
    // produce(g+2)'s overwrite of the same parity in program order (DS in-order).
    float w = 0.f;
    auto wsum16 = [&](int g) {
        const int base = 672 - 112 * g;
        const int r0   = (wv - 1) * 16;
        const float (*hw)[64] = hb16[g & 1][wv - 1];
#pragma unroll
        for (int i = 0; i < 16; ++i)
            w = fmaf(a_lds[base + r0 + i], hw[i][lane], w);
    };

    // ---- phase 0: wave0 u-init || producers produce(0)+gram8(0) ----
    float4 uq = make_float4(0.f, 0.f, 0.f, 0.f);
    if (wv == 0) {
        const float h = gelu_exact(fmaf(x[b * SEQ + 783], win, pos_emb[783 * 64 + lane]));
        sh[lane] = h;
        WAVE_FENCE();
        float u = 0.f;
        const float4* wq4 = (const float4*)(Wq + lane * 64);
        const float4* h4  = (const float4*)sh;
#pragma unroll
        for (int i = 0; i < 16; ++i) {
            float4 hv = h4[i], qv = wq4[i];
            u = fmaf(hv.x, qv.x, u);
            u = fmaf(hv.y, qv.y, u);
            u = fmaf(hv.z, qv.z, u);
            u = fmaf(hv.w, qv.w, u);
        }
        WAVE_FENCE();
        sh[lane] = u;
        WAVE_FENCE();
        uq = ((const float4*)sh)[lane & 15];   // replicated slice layout
    } else {
        produce(0, 0);
        WAVE_FENCE();
        gram8(0);
    }
    __syncthreads();

    // oct-Gram scan block (validated): 8 pipelined D-reductions + uniform
    // Gram reads + pure-VALU triangular solve + one u-update.
    auto scan8 = [&](int buf, int T0, int beta) {
        const int rb = 111 - 8 * beta;
        const int T  = T0 - 8 * beta;
        const float4 k0 = ((const float4*)kbuf[buf][rb    ])[lane & 15];
        const float4 k1 = ((const float4*)kbuf[buf][rb - 1])[lane & 15];
        const float4 k2 = ((const float4*)kbuf[buf][rb - 2])[lane & 15];
        const float4 k3 = ((const float4*)kbuf[buf][rb - 3])[lane & 15];
        const float4 k4 = ((const float4*)kbuf[buf][rb - 4])[lane & 15];
        const float4 k5 = ((const float4*)kbuf[buf][rb - 5])[lane & 15];
        const float4 k6 = ((const float4*)kbuf[buf][rb - 6])[lane & 15];
        const float4 k7 = ((const float4*)kbuf[buf][rb - 7])[lane & 15];
        const float4 avH = *(const float4*)&al_lds[T - 3];  // al0=.w .. al3=.x
        const float4 avL = *(const float4*)&al_lds[T - 7];  // al4=.w .. al7=.x
        const float* Gb = &G_blk[buf][beta][0][0];
        const float g01 = Gb[1],  g02 = Gb[2],  g03 = Gb[3],  g04 = Gb[4];
        const float g05 = Gb[5],  g06 = Gb[6],  g07 = Gb[7];
        const float g12 = Gb[10], g13 = Gb[11], g14 = Gb[12], g15 = Gb[13];
        const float g16 = Gb[14], g17 = Gb[15];
        const float g23 = Gb[19], g24 = Gb[20], g25 = Gb[21], g26 = Gb[22];
        const float g27 = Gb[23];
        const float g34 = Gb[28], g35 = Gb[29], g36 = Gb[30], g37 = Gb[31];
        const float g45 = Gb[37], g46 = Gb[38], g47 = Gb[39];
        const float g56 = Gb[46], g57 = Gb[47];
        const float g67 = Gb[55];
        const float D0 = row16_allsum(dot4(uq, k0));
        const float D1 = row16_allsum(dot4(uq, k1));
        const float D2 = row16_allsum(dot4(uq, k2));
        const float D3 = row16_allsum(dot4(uq, k3));
        const float D4 = row16_allsum(dot4(uq, k4));
        const float D5 = row16_allsum(dot4(uq, k5));
        const float D6 = row16_allsum(dot4(uq, k6));
        const float D7 = row16_allsum(dot4(uq, k7));
        const float a0 = avH.w * D0;
        const float d1 = fmaf(-a0, g01, D1);
        const float a1 = avH.z * d1;
        const float d2 = fmaf(-a1, g12, fmaf(-a0, g02, D2));
        const float a2 = avH.y * d2;
        const float d3 = fmaf(-a2, g23, fmaf(-a1, g13, fmaf(-a0, g03, D3)));
        const float a3 = avH.x * d3;
        const float d4 = fmaf(-a3, g34, fmaf(-a2, g24, fmaf(-a1, g14, fmaf(-a0, g04, D4))));
        const float a4 = avL.w * d4;
        const float d5 = fmaf(-a4, g45, fmaf(-a3, g35, fmaf(-a2, g25, fmaf(-a1, g15, fmaf(-a0, g05, D5)))));
        const float a5 = avL.z * d5;
        const float d6 = fmaf(-a5, g56, fmaf(-a4, g46, fmaf(-a3, g36, fmaf(-a2, g26, fmaf(-a1, g16, fmaf(-a0, g06, D6))))));
        const float a6 = avL.y * d6;
        const float d7 = fmaf(-a6, g67, fmaf(-a5, g57, fmaf(-a4, g47, fmaf(-a3, g37, fmaf(-a2, g27, fmaf(-a1, g17, fmaf(-a0, g07, D7)))))));
        const float a7 = avL.x * d7;
        uq.x = fmaf(-a7, k7.x, fmaf(-a6, k6.x, fmaf(-a5, k5.x, fmaf(-a4, k4.x,
               fmaf(-a3, k3.x, fmaf(-a2, k2.x, fmaf(-a1, k1.x, fmaf(-a0, k0.x, uq.x))))))));
        uq.y = fmaf(-a7, k7.y, fmaf(-a6, k6.y, fmaf(-a5, k5.y, fmaf(-a4, k4.y,
               fmaf(-a3, k3.y, fmaf(-a2, k2.y, fmaf(-a1, k1.y, fmaf(-a0, k0.y, uq.y))))))));
        uq.z = fmaf(-a7, k7.z, fmaf(-a6, k6.z, fmaf(-a5, k5.z, fmaf(-a4, k4.z,
               fmaf(-a3, k3.z, fmaf(-a2, k2.z, fmaf(-a1, k1.z, fmaf(-a0, k0.z, uq.z))))))));
        uq.w = fmaf(-a7, k7.w, fmaf(-a6, k6.w, fmaf(-a5, k5.w, fmaf(-a4, k4.w,
               fmaf(-a3, k3.w, fmaf(-a2, k2.w, fmaf(-a1, k1.w, fmaf(-a0, k0.w, uq.w))))))));
        if (lane == 0) {
            *(float4*)&a_lds[T - 3] = make_float4(a3, a2, a1, a0);
            *(float4*)&a_lds[T - 7] = make_float4(a7, a6, a5, a4);
        }
    };

    // ---- main loop: wave0 scans g; producers wsum(g-1) + produce/gram(g+1) ----
#pragma unroll 1
    for (int g = 0; g < 7; ++g) {
        const int buf = g & 1;
        const int T0  = 783 - 112 * g;
        if (wv == 0) {
#pragma unroll 1
            for (int beta = 0; beta < 14; ++beta)
                scan8(buf, T0, beta);
        } else {
            if (g >= 1) wsum16(g - 1);
            if (g < 6) {
                produce(g + 1, buf ^ 1);
                WAVE_FENCE();
                gram8(buf ^ 1);
            }
        }
        __syncthreads();
    }

    // ---- tail: producers wsum group 6 (a(6) barrier-ordered; h(6) in hb16[0]) ----
    if (wv != 0) wsum16(6);
    swr[wv][lane] = (wv == 0) ? 0.f : w;
    __syncthreads();
    if (wv != 0) return;

    // ---- wave-0 epilogue: last = Wv*w -> LN -> logits ----
    w = swr[0][lane] + swr[1][lane] + swr[2][lane] + swr[3][lane]
      + swr[4][lane] + swr[5][lane] + swr[6][lane] + swr[7][lane];
    sh[lane] = w;
    WAVE_FENCE();
    float last = 0.f;
    const float4* wv4 = (const float4*)(Wv + lane * 64);
    const float4* w4  = (const float4*)sh;
#pragma unroll
    for (int i = 0; i < 16; ++i) {
        float4 hv = w4[i], vv = wv4[i];
        last = fmaf(hv.x, vv.x, last);
        last = fmaf(hv.y, vv.y, last);
        last = fmaf(hv.z, vv.z, last);
        last = fmaf(hv.w, vv.w, last);
    }
    const float mu  = wave_allsum(last) * 0.015625f;
    const float dd  = last - mu;
    const float var = wave_allsum(dd * dd) * 0.015625f;
    const float ln  = dd / sqrtf(var + 1e-5f) * ln_g[lane] + ln_b[lane];
    WAVE_FENCE();
    sh[lane] = ln;
    WAVE_FENCE();
    if (lane < 10) {
        float acc = bc[lane];
        const float* wc = Wc + lane * 64;
#pragma unroll
        for (int j = 0; j < 64; ++j) acc = fmaf(wc[j], sh[j], acc);
        out[b * 10 + lane] = acc;
    }
}

extern "C" void kernel_launch(void* const* d_in, const int* in_sizes, int n_in,
                              void* d_out, int out_size, void* d_ws, size_t ws_size,
                              hipStream_t stream)
{
    const float* x       = (const float*)d_in[0];
    const float* W_in    = (const float*)d_in[1];
    const float* pos_emb = (const float*)d_in[2];
    const float* Wq      = (const float*)d_in[3];
    const float* Wk      = (const float*)d_in[4];
    const float* Wv      = (const float*)d_in[5];
    const float* Wb      = (const float*)d_in[6];
    const float* bb      = (const float*)d_in[7];
    const float* ln_g    = (const float*)d_in[8];
    const float* ln_b    = (const float*)d_in[9];
    const float* Wc      = (const float*)d_in[10];
    const float* bc      = (const float*)d_in[11];
    float* out = (float*)d_out;

    fused_all<<<BATCH, 512, 0, stream>>>(x, W_in, pos_emb, Wq, Wk, Wv, Wb, bb,
                                         ln_g, ln_b, Wc, bc, out);
}